// Round 6
// baseline (170.979 us; speedup 1.0000x reference)
//
#include <hip/hip_runtime.h>

// LatticeFilter: step-up (Levinson-Durbin) recursion, rc -> LPC coeffs.
//   rc: (B=16, p=128, Tf=8192) fp32, k_i = 0.98*rc[b,i,t]
//   out: (B, Tf, p+1=129) fp32, a[...,0]=1
//
// R11. Sharpened front-end model (validated on R5/R8/R10):
//   wall(straight-line kernel, text > L1I) ~= text_lines x ~130cy, SERIAL,
//   regardless of occupancy, lockstep, or memory overlap (R10: forced
//   lockstep = 60us ~= R5 desynced 52.8us ~= 1016 lines x ~130cy).
//   text <= L1I (R8-A, 13KB) -> BW floor: only the first pass per CU pays.
// => The only lever is making every kernel's text fit the I$.
//
// R11 = R9's plan executed correctly (R9 died of a dropped waves_per_eu:
// default 8-wave/EU target squeezed VGPR to 60/88 -> scratch, 90+90us):
//   - 2-way split at fmac-equal boundary S=90; state a[1..90] parked in
//     its FINAL out positions (no extra storage, no races, exact fp32 RT)
//   - pair update via inline-asm v_fmac_f32 (VOP2 4B): mov+2 fmac =
//     12B/pair vs 16B -> A ~26.3KB, B ~26.5KB text, both < 32KB L1I
//   - amdgpu_waves_per_eu(2,2) pinned on BOTH kernels (256-reg budget)
// Live sets flat: A ~95 (kq dies as a grows), B ~135; both << 256 arch cap.
// fmac = same fused op, same order -> bit-identical results.
// Floors: A 94.4MB -> ~15us, B 134.7MB -> ~21.4us; sum ~36 vs R5 52.8.
// Falsifier: B ~58us unchanged => L1I < 27KB => pivot (no-split fmac ~42us).

#define NB    16
#define ORD   128
#define TF    8192
#define SPLIT 90

// ---- pair update j <-> m-j, VOP2 v_fmac encoding (4B vs VOP3 fma 8B) ----
// a[J] += k*a[M-J];  a[M-J] += k*a[J]_old   (old copy = 1 v_mov, 4B)
template<int M, int J>
struct PairUpd {
    static __device__ __forceinline__ void run(float (&a)[ORD + 1], float k) {
        const float lo = a[J];                  // old value (one v_mov)
        asm("v_fmac_f32 %0, %1, %2" : "+v"(a[J])     : "v"(k), "v"(a[M - J]));
        asm("v_fmac_f32 %0, %1, %2" : "+v"(a[M - J]) : "v"(k), "v"(lo));
        if constexpr (2 * (J + 1) < M) PairUpd<M, J + 1>::run(a, k);
    }
};

// Steps M..MEND; k from kq[M-1-K0]
template<int M, int MEND, int K0, int NK>
struct Step {
    static __device__ __forceinline__ void run(float (&a)[ORD + 1],
                                               const float (&kq)[NK]) {
        const float k = 0.98f * kq[M - 1 - K0];
        if constexpr (M > 2) PairUpd<M, 1>::run(a, k);
        if constexpr ((M & 1) == 0) {            // middle: a[M/2] += k*a[M/2]
            const float mid = a[M / 2];
            asm("v_fmac_f32 %0, %1, %2" : "+v"(a[M / 2]) : "v"(k), "v"(mid));
        }
        a[M] = k;                                // a[0] == 1 contributes k
        if constexpr (M < MEND) Step<M + 1, MEND, K0, NK>::run(a, kq);
    }
};

// ---- LDS staging, static indices (compiler merges into ds_write_b128) ----
template<int J>
struct Stage {
    static __device__ __forceinline__ void run(float* __restrict__ dst,
                                               const float (&a)[ORD + 1]) {
        dst[J] = a[J];
        if constexpr (J < ORD) Stage<J + 1>::run(dst, a);
    }
};

// =======================  Kernel A: steps 1..SPLIT  =======================
// ~26.3KB text < L1I. Writes a[1..SPLIT] to out[col*129+j] (final slots).
__global__ __launch_bounds__(256)
__attribute__((amdgpu_waves_per_eu(2, 2)))   // pin 256-reg budget (R9 lesson)
void lpc_stepA(const float* __restrict__ rc, float* __restrict__ out) {
    const int col = blockIdx.x * 256 + threadIdx.x;   // flattened (B*Tf) column
    const int b = col >> 13;
    const int t = col & (TF - 1);
    const float* rcp = rc + ((size_t)b * ORD) * TF + t;

    float kq[SPLIT];                                  // full prefetch: pressure
#pragma unroll                                        // flat (kq dies as a grows)
    for (int i = 0; i < SPLIT; ++i) kq[i] = rcp[(size_t)i * TF];

    float a[ORD + 1];
    a[0] = 1.0f;
    Step<1, SPLIT, 0, SPLIT>::run(a, kq);

    // state -> final out positions; strided dwords (lines collectively full)
    float* op = out + (size_t)col * (ORD + 1);
#pragma unroll
    for (int j = 1; j <= SPLIT; ++j) op[j] = a[j];
}

// =====================  Kernel B: steps SPLIT+1..128  =====================
// ~26.5KB text < L1I. Reads state back, finishes, writes full rows via the
// proven conflict-free LDS transpose (stride 129 -> bank stride 1).
__global__ __launch_bounds__(128)
__attribute__((amdgpu_waves_per_eu(2, 2)))   // pin 256-reg budget
void lpc_stepB(const float* __restrict__ rc, float* out) {
    const int tid = threadIdx.x;
    const int col = blockIdx.x * 128 + tid;
    const int b = col >> 13;
    const int t = col & (TF - 1);
    const float* rcp = rc + ((size_t)b * ORD) * TF + t;

    constexpr int NK = ORD - SPLIT;                   // 38 remaining k's
    float kq[NK];
#pragma unroll
    for (int i = 0; i < NK; ++i) kq[i] = rcp[(size_t)(SPLIT + i) * TF];

    float a[ORD + 1];
    a[0] = 1.0f;
    {   // reload state from final out positions (per-lane strided dwords)
        const float* op = out + (size_t)col * (ORD + 1);
#pragma unroll
        for (int j = 1; j <= SPLIT; ++j) a[j] = op[j];
    }

    Step<SPLIT + 1, ORD, SPLIT, NK>::run(a, kq);

    // ---- epilogue: transpose 128 rows x 129 cols through LDS, 2 rounds ----
    __shared__ __align__(16) float lds[64 * (ORD + 1)];   // 33,024 B
    const int my_round = tid >> 6;                    // wave index, uniform branch
    const int row      = tid & 63;

    for (int r = 0; r < 2; ++r) {
        __syncthreads();
        if (my_round == r)
            Stage<0>::run(&lds[row * (ORD + 1)], a);
        __syncthreads();
        const float4* lds4 = (const float4*)lds;
        float4* out4 = (float4*)(out + (size_t)(blockIdx.x * 128 + r * 64) * (ORD + 1));
#pragma unroll 4
        for (int e = tid; e < (64 * (ORD + 1)) / 4; e += 128)
            out4[e] = lds4[e];                        // perfectly coalesced
    }
}

extern "C" void kernel_launch(void* const* d_in, const int* in_sizes, int n_in,
                              void* d_out, int out_size, void* d_ws, size_t ws_size,
                              hipStream_t stream) {
    // d_in[0] = excitation (dead in reference), d_in[1] = rc
    const float* rc = (const float*)d_in[1];
    float* out = (float*)d_out;
    hipLaunchKernelGGL(lpc_stepA, dim3((NB * TF) / 256), dim3(256), 0, stream, rc, out);
    hipLaunchKernelGGL(lpc_stepB, dim3((NB * TF) / 128), dim3(128), 0, stream, rc, out);
}